// Round 15
// baseline (1986.094 us; speedup 1.0000x reference)
//
#include <hip/hip_runtime.h>

#define NB 4
#define NN 8192
#define NS 2048
#define NK 32
#define NCF 64
#define R2 0.04f

// ws layout in float units
#define WS_FPSIDX 0              // int[NB*NS]           = 8192
#define WS_PACK   8192           // float4[NB*NN]        = 131072 floats
#define WS_GIDX   139264         // int[NB*NS*NK]        = 262144
#define WS_WT0    401408         // 67*64
#define WS_BB0    405696         // 64
#define WS_WT1    405760         // 64*64
#define WS_BB1    409856         // 64
#define WS_WT2    409920         // 64*128
#define WS_BB2    418112         // 128

__device__ __forceinline__ unsigned long long umax64(unsigned long long a,
                                                     unsigned long long b) {
  return a > b ? a : b;   // v_cmp_lt_u64 + cndmask pair
}

template <int CTRL>
__device__ __forceinline__ void dpp_max64(unsigned& kl, unsigned& kh) {
  // 64-bit max ladder step: bound_ctrl=true -> shifted-in lanes see key=0,
  // which never wins (real keys have kl > 0).
  unsigned nl = (unsigned)__builtin_amdgcn_update_dpp(0, (int)kl, CTRL, 0xf, 0xf, true);
  unsigned nh = (unsigned)__builtin_amdgcn_update_dpp(0, (int)kh, CTRL, 0xf, 0xf, true);
  unsigned long long cur = ((unsigned long long)kh << 32) | kl;
  unsigned long long oth = ((unsigned long long)nh << 32) | nl;
  bool take = oth > cur;
  kl = take ? nl : kl;
  kh = take ? nh : kh;
}

template <int CTRL>
__device__ __forceinline__ float dpp_fmin2(float x) {
  // bound_ctrl=false + old=x: invalid lanes contribute x itself (idempotent).
  int t = __builtin_amdgcn_update_dpp(__float_as_int(x), __float_as_int(x),
                                      CTRL, 0xf, 0xf, false);
  return fminf(x, __int_as_float(t));
}
template <int CTRL>
__device__ __forceinline__ float dpp_fmax2(float x) {
  int t = __builtin_amdgcn_update_dpp(__float_as_int(x), __float_as_int(x),
                                      CTRL, 0xf, 0xf, false);
  return fmaxf(x, __int_as_float(t));
}
__device__ __forceinline__ float wave_min_bcast(float x) {
  x = dpp_fmin2<0x111>(x); x = dpp_fmin2<0x112>(x); x = dpp_fmin2<0x114>(x);
  x = dpp_fmin2<0x118>(x); x = dpp_fmin2<0x142>(x); x = dpp_fmin2<0x143>(x);
  return __int_as_float(__builtin_amdgcn_readlane(__float_as_int(x), 63));
}
__device__ __forceinline__ float wave_max_bcast(float x) {
  x = dpp_fmax2<0x111>(x); x = dpp_fmax2<0x112>(x); x = dpp_fmax2<0x114>(x);
  x = dpp_fmax2<0x118>(x); x = dpp_fmax2<0x142>(x); x = dpp_fmax2<0x143>(x);
  return __int_as_float(__builtin_amdgcn_readlane(__float_as_int(x), 63));
}

__device__ __forceinline__ int morton12(int ix, int iy, int iz) {
  // 4 bits each (16^3 grid), interleaved: bit k -> bit 3k.
  auto sp = [](int v) {
    return (v & 1) | ((v & 2) << 2) | ((v & 4) << 4) | ((v & 8) << 6);
  };
  return sp(ix) | (sp(iy) << 1) | (sp(iz) << 2);
}

// ---------------------------------------------------------------------------
// FPS: one block per batch, 1024 threads (16 waves), 8 points/thread.
// Exact semantics preserved: dist init 1e10f, far0=0,
// d = ((dx*dx+dy*dy)+dz*dz) with NO fma contraction; dist=min(dist,d);
// argmax first-index tiebreak via u64 keys.
// Key low word: (8191-idx)<<5 | wid. idx is unique and dominates the wid
// bits, so unsigned key order == (dist desc, idx asc) EXACTLY; the winning
// wave's slot id rides for free.
// 16^3 Morton-binned waves own compact 512-pt runs with exact float
// register bboxes; a wave updates only if lb(bbox,c)^2*0.999 < cachedmax
// (skip is provably a no-op; cached key republished -> bit-identical).
//
// R15 change: the dependent post-ladder center read is replaced by a
// PREFETCH: right after the skey read, lane l loads candidate l's coords
// (overlaps the 4-step ladder), and 3 slot-indexed readlanes deliver the
// winner's coords -- removing ~80-120 cyc from every wave's serial chain.
// ---------------------------------------------------------------------------
__global__ __launch_bounds__(1024)
void fps_kernel(const float* __restrict__ xyz, int* __restrict__ fps_idx,
                float* __restrict__ new_xyz)
{
#pragma clang fp contract(off)
  const int b = blockIdx.x;
  const int tid = threadIdx.x;
  const int lane = tid & 63;
  const int wid = tid >> 6;
  const float* __restrict__ P = xyz + (size_t)b * (NN * 3);

  __shared__ float Pl[NN * 3];                 // 96 KB staged coords
  __shared__ unsigned short sidx[NN];          // 16 KB binned orig indices
  __shared__ int hist[4096];                   // 16 KB fine-cell histogram
  __shared__ int hsum[64];                     // chunk partial sums (scan)
  __shared__ unsigned long long skey[2][16];   // double-buffered wave keys

  // ---- one-time: stage coords, Morton-bin (16^3), scatter ----
  {
    const float4* __restrict__ src = (const float4*)P;
    float4* dst = (float4*)Pl;
#pragma unroll
    for (int i = 0; i < 6; ++i) dst[tid + i * 1024] = src[tid + i * 1024];
  }
#pragma unroll
  for (int i = 0; i < 4; ++i) hist[tid + i * 1024] = 0;
  __syncthreads();

  unsigned short mycell[8];
#pragma unroll
  for (int j = 0; j < 8; ++j) {
    int p = tid + j * 1024;
    float x = Pl[p * 3 + 0], y = Pl[p * 3 + 1], z = Pl[p * 3 + 2];
    int ix = min(15, max(0, (int)(x * 16.0f)));
    int iy = min(15, max(0, (int)(y * 16.0f)));
    int iz = min(15, max(0, (int)(z * 16.0f)));
    int cell = morton12(ix, iy, iz);
    mycell[j] = (unsigned short)cell;
    atomicAdd(&hist[cell], 1);
  }
  __syncthreads();
  // ---- 3-phase exclusive prefix over 4096 cells (one-time) ----
  if (tid < 64) {
    int acc = 0;
    for (int c = 0; c < 64; ++c) {
      int h = hist[tid * 64 + c];
      hist[tid * 64 + c] = acc;
      acc += h;
    }
    hsum[tid] = acc;
  }
  __syncthreads();
  if (tid == 0) {
    int acc = 0;
    for (int c = 0; c < 64; ++c) { int h = hsum[c]; hsum[c] = acc; acc += h; }
  }
  __syncthreads();
#pragma unroll
  for (int i = 0; i < 4; ++i) {
    int c = tid + i * 1024;
    hist[c] += hsum[c >> 6];
  }
  __syncthreads();
#pragma unroll
  for (int j = 0; j < 8; ++j) {
    int p = tid + j * 1024;
    int pos = atomicAdd(&hist[mycell[j]], 1);
    sidx[pos] = (unsigned short)p;
  }
  __syncthreads();

  // ---- load my 8 binned points + keys; wave slots are contiguous 512 ----
  float px[8], py[8], pz[8], dist[8];
  unsigned klc[8];
#pragma unroll
  for (int j = 0; j < 8; ++j) {
    int slot = wid * 512 + j * 64 + lane;
    int p = sidx[slot];
    px[j] = Pl[p * 3 + 0];
    py[j] = Pl[p * 3 + 1];
    pz[j] = Pl[p * 3 + 2];
    dist[j] = 1e10f;
    klc[j] = ((unsigned)(8191 - p) << 5) | (unsigned)wid;  // idx dominates
  }
  // ---- wave bbox (registers, broadcast via readlane) ----
  float mnx = fminf(fminf(fminf(px[0], px[1]), fminf(px[2], px[3])),
                    fminf(fminf(px[4], px[5]), fminf(px[6], px[7])));
  float mxx = fmaxf(fmaxf(fmaxf(px[0], px[1]), fmaxf(px[2], px[3])),
                    fmaxf(fmaxf(px[4], px[5]), fmaxf(px[6], px[7])));
  float mny = fminf(fminf(fminf(py[0], py[1]), fminf(py[2], py[3])),
                    fminf(fminf(py[4], py[5]), fminf(py[6], py[7])));
  float mxy = fmaxf(fmaxf(fmaxf(py[0], py[1]), fmaxf(py[2], py[3])),
                    fmaxf(fmaxf(py[4], py[5]), fmaxf(py[6], py[7])));
  float mnz = fminf(fminf(fminf(pz[0], pz[1]), fminf(pz[2], pz[3])),
                    fminf(fminf(pz[4], pz[5]), fminf(pz[6], pz[7])));
  float mxz = fmaxf(fmaxf(fmaxf(pz[0], pz[1]), fmaxf(pz[2], pz[3])),
                    fmaxf(fmaxf(pz[4], pz[5]), fmaxf(pz[6], pz[7])));
  const float blx = wave_min_bcast(mnx), bhx = wave_max_bcast(mxx);
  const float bly = wave_min_bcast(mny), bhy = wave_max_bcast(mxy);
  const float blz = wave_min_bcast(mnz), bhz = wave_max_bcast(mxz);

  float cx = P[0], cy = P[1], cz = P[2];   // first center = point 0
  int far = 0;
  unsigned ckl = 0u, ckh = 0u;             // cached wave key (lane 63 holds it)
  float cachedmax = 1e10f;                 // forces update at k=0

  for (int k = 0; k < NS; ++k) {
    if (tid == 0) {
      fps_idx[b * NS + k] = far;
      float* o = new_xyz + ((size_t)b * NS + k) * 3;
      o[0] = cx; o[1] = cy; o[2] = cz;
    }
    if (k == NS - 1) break;

    // ---- bbox pruning test (wave-uniform; skip is provably a no-op) ----
    float dlx = fmaxf(fmaxf(blx - cx, cx - bhx), 0.0f);
    float dly = fmaxf(fmaxf(bly - cy, cy - bhy), 0.0f);
    float dlz = fmaxf(fmaxf(blz - cz, cz - bhz), 0.0f);
    float dlb = dlx * dlx + dly * dly + dlz * dlz;
    int doupd = __builtin_amdgcn_readfirstlane(
        (int)!(dlb * 0.999f >= cachedmax));
    if (doupd) {
      // ---- distance update (exact math) + u64 key build
      unsigned long long k8[8];
#pragma unroll
      for (int j = 0; j < 8; ++j) {
        float dx = px[j] - cx;
        float dy = py[j] - cy;
        float dz = pz[j] - cz;
        float d = (dx * dx + dy * dy) + dz * dz;   // plain mul/add, l-to-r
        float t = fminf(dist[j], d);
        dist[j] = t;
        k8[j] = ((unsigned long long)(unsigned)__float_as_int(t) << 32) | klc[j];
      }
      unsigned long long t0 = umax64(k8[0], k8[1]);
      unsigned long long t1 = umax64(k8[2], k8[3]);
      unsigned long long t2 = umax64(k8[4], k8[5]);
      unsigned long long t3 = umax64(k8[6], k8[7]);
      unsigned long long bk = umax64(umax64(t0, t1), umax64(t2, t3));

      unsigned kl = (unsigned)bk, kh = (unsigned)(bk >> 32);
      dpp_max64<0x111>(kl, kh);
      dpp_max64<0x112>(kl, kh);
      dpp_max64<0x114>(kl, kh);
      dpp_max64<0x118>(kl, kh);
      dpp_max64<0x142>(kl, kh);
      dpp_max64<0x143>(kl, kh);
      ckl = kl; ckh = kh;
      cachedmax = __int_as_float(__builtin_amdgcn_readlane((int)kh, 63));
    }

    const int ws = k & 1;
    if (lane == 63) {
      skey[ws][wid] = ((unsigned long long)ckh << 32) | ckl;
    }
    __syncthreads();

    // ---- cross-wave reduce over 16 u64 keys; candidate-coord prefetch
    //      overlaps the ladder (independent LDS reads issued first)
    unsigned long long sk = skey[ws][lane & 15];
    unsigned skl = (unsigned)sk, skh = (unsigned)(sk >> 32);
    int cand = 8191 - (int)(skl >> 5);           // candidate idx of slot (lane&15)
    const float* cp = Pl + cand * 3;
    float ccx = cp[0], ccy = cp[1], ccz = cp[2]; // prefetched, indep of ladder
    dpp_max64<0x111>(skl, skh);
    dpp_max64<0x112>(skl, skh);
    dpp_max64<0x114>(skl, skh);
    dpp_max64<0x118>(skl, skh);  // lane15 of each row = block max
    unsigned kl15 = (unsigned)__builtin_amdgcn_readlane((int)skl, 15);
    far = 8191 - (int)(kl15 >> 5);
    int slot = (int)(kl15 & 31u);                // winning wave's slot id
    cx = __int_as_float(__builtin_amdgcn_readlane(__float_as_int(ccx), slot));
    cy = __int_as_float(__builtin_amdgcn_readlane(__float_as_int(ccy), slot));
    cz = __int_as_float(__builtin_amdgcn_readlane(__float_as_int(ccz), slot));
  }
}

// ---------------------------------------------------------------------------
// pack = {x, y, z, (x*x+y*y)+z*z} per point (sq matches jnp.sum(xyz**2,-1))
// ---------------------------------------------------------------------------
__global__ void prep_pack(const float* __restrict__ xyz, float4* __restrict__ pack)
{
#pragma clang fp contract(off)
  int t = blockIdx.x * 256 + threadIdx.x;
  if (t < NB * NN) {
    float x = xyz[t * 3 + 0], y = xyz[t * 3 + 1], z = xyz[t * 3 + 2];
    float4 v; v.x = x; v.y = y; v.z = z; v.w = (x * x + y * y) + z * z;
    pack[t] = v;
  }
}

// ---------------------------------------------------------------------------
// Fold BN into weights, transpose to (c,o), remap layer0 channels so that
// c'=0..63 are features (orig 3..66) and c'=64..66 are rel-xyz (orig 0..2).
// ---------------------------------------------------------------------------
__global__ void prep_w(
    const float* __restrict__ w0, const float* __restrict__ b0,
    const float* __restrict__ g0, const float* __restrict__ be0,
    const float* __restrict__ m0, const float* __restrict__ v0,
    const float* __restrict__ w1, const float* __restrict__ b1,
    const float* __restrict__ g1, const float* __restrict__ be1,
    const float* __restrict__ m1, const float* __restrict__ v1,
    const float* __restrict__ w2, const float* __restrict__ b2,
    const float* __restrict__ g2, const float* __restrict__ be2,
    const float* __restrict__ m2, const float* __restrict__ v2,
    float* __restrict__ wT0, float* __restrict__ bb0,
    float* __restrict__ wT1, float* __restrict__ bb1,
    float* __restrict__ wT2, float* __restrict__ bb2)
{
  int t = blockIdx.x * 256 + threadIdx.x;
  if (t < 4288) {
    int c = t >> 6, o = t & 63;
    int oc = (c < 64) ? (c + 3) : (c - 64);
    float sc = g0[o] * rsqrtf(v0[o] + 1e-5f);
    wT0[t] = w0[o * 67 + oc] * sc;
  } else if (t < 4352) {
    int o = t - 4288;
    float sc = g0[o] * rsqrtf(v0[o] + 1e-5f);
    bb0[o] = (b0[o] - m0[o]) * sc + be0[o];
  } else if (t < 8448) {
    int u = t - 4352;
    int c = u >> 6, o = u & 63;
    float sc = g1[o] * rsqrtf(v1[o] + 1e-5f);
    wT1[u] = w1[o * 64 + c] * sc;
  } else if (t < 8512) {
    int o = t - 8448;
    float sc = g1[o] * rsqrtf(v1[o] + 1e-5f);
    bb1[o] = (b1[o] - m1[o]) * sc + be1[o];
  } else if (t < 16704) {
    int u = t - 8512;
    int c = u >> 7, o = u & 127;
    float sc = g2[o] * rsqrtf(v2[o] + 1e-5f);
    wT2[u] = w2[o * 64 + c] * sc;
  } else if (t < 16832) {
    int o = t - 16704;
    float sc = g2[o] * rsqrtf(v2[o] + 1e-5f);
    bb2[o] = (b2[o] - m2[o]) * sc + be2[o];
  }
}

// ---------------------------------------------------------------------------
// Ball query: one wave per query point. sqr = (sq_q + sq_x) - 2*dot with
// dot as Eigen-style fma chain over (x,y,z). Packed {x,y,z,sq} float4 loads
// (1 dwordx4/point). First 32 in-ball indices ascending; pad with first hit.
// ---------------------------------------------------------------------------
__global__ __launch_bounds__(256)
void ballq_kernel(const float4* __restrict__ pack,
                  const int* __restrict__ fps_idx, int* __restrict__ gidx)
{
#pragma clang fp contract(off)
  const int lane = threadIdx.x & 63;
  const int q = blockIdx.x * 4 + (threadIdx.x >> 6);
  const int b = q >> 11;
  const int s = q & 2047;
  const float4* __restrict__ PK = pack + (size_t)b * NN;
  const int cidx = fps_idx[b * NS + s];
  const float4 c4 = PK[cidx];
  const float cx = c4.x, cy = c4.y, cz = c4.z, csq = c4.w;
  int* __restrict__ g = gidx + (size_t)q * NK;
  int cnt = 0, firstn = 0;
  bool havefirst = false;
  for (int n0 = 0; n0 < NN; n0 += 64) {
    int n = n0 + lane;
    float4 p4 = PK[n];
    float dot = p4.x * cx;         // first gebp step: fma(a0,b0,0) == rn(a0*b0)
    dot = fmaf(p4.y, cy, dot);
    dot = fmaf(p4.z, cz, dot);
    float sqr = (csq + p4.w) - 2.0f * dot;
    bool in_ = (sqr <= R2);
    unsigned long long m = __ballot(in_);
    if (!havefirst && m) { firstn = n0 + __builtin_ctzll(m); havefirst = true; }
    int pos = cnt + __popcll(m & ((1ull << lane) - 1ull));
    if (in_ && pos < NK) g[pos] = n;
    cnt += __popcll(m);
    if (cnt >= NK) break;
  }
  if (cnt < NK && lane < NK - cnt) g[cnt + lane] = firstn;
}

// ---------------------------------------------------------------------------
// Grouped MLP + k-max: one block (256 thr) per query. Activations in LDS;
// weights staged per layer into one reused 32KB LDS buffer (R12 win).
// R15: 2-row register blocking -- thread (k2,jj) computes rows k2 and k2+16,
// so every weight b128 read feeds TWO activation rows (LDS reads per 32
// FMAs: 9 -> 6 on L1/L2, 18 -> 10 on L3). Per-output accumulation order is
// unchanged (c ascending) -> bit-identical. ReLU of layer 3 deferred past
// the max (relu(max) == max(relu)).
// ---------------------------------------------------------------------------
__global__ __launch_bounds__(256)
void mlp_kernel(const float* __restrict__ xyz, const float* __restrict__ feat,
                const int* __restrict__ gidx, const float* __restrict__ nxyz,
                const float* __restrict__ wT0, const float* __restrict__ bb0,
                const float* __restrict__ wT1, const float* __restrict__ bb1,
                const float* __restrict__ wT2, const float* __restrict__ bb2,
                float* __restrict__ out)
{
  const int q = blockIdx.x;
  const int b = q >> 11;
  const int tid = threadIdx.x;
  __shared__ int sg[32];
  __shared__ float A[32 * 76];    // stride 76 (=19*4): 16B-aligned rows
  __shared__ float Bf[32 * 76];
  __shared__ float Cf[32 * 132];
  __shared__ float Wb[8192];      // 32KB reused weight buffer (max 64*128)
  if (tid < 32) sg[tid] = gidx[(size_t)q * NK + tid];
  __syncthreads();
  {
    const int k = tid >> 3, j = tid & 7;
    const int p = sg[k];
    const float* fp = feat + ((size_t)b * NN + p) * NCF + j * 8;
    float4 f0 = *(const float4*)fp;
    float4 f1 = *(const float4*)(fp + 4);
    float* a = &A[k * 76 + j * 8];
    *(float4*)a = f0;
    *(float4*)(a + 4) = f1;
    if (j == 0) {
      float cx = nxyz[(size_t)q * 3 + 0];
      float cy = nxyz[(size_t)q * 3 + 1];
      float cz = nxyz[(size_t)q * 3 + 2];
      const float* pp = xyz + ((size_t)b * NN + p) * 3;
      A[k * 76 + 64] = pp[0] - cx;
      A[k * 76 + 65] = pp[1] - cy;
      A[k * 76 + 66] = pp[2] - cz;
    }
  }
  // ---- stage W0 (67*64 = 4288 floats = 1072 float4)
  {
    const float4* src = (const float4*)wT0;
    float4* dst = (float4*)Wb;
    for (int i = tid; i < 1072; i += 256) dst[i] = src[i];
  }
  __syncthreads();

  const int k2 = tid >> 4;       // row pair: k2 and k2+16
  const int jj = tid & 15;
#define FMA4x2(gA, gB, base)                                                \
  {                                                                         \
    float4 w = *(const float4*)(base);                                      \
    aA.x = fmaf(gA, w.x, aA.x); aA.y = fmaf(gA, w.y, aA.y);                 \
    aA.z = fmaf(gA, w.z, aA.z); aA.w = fmaf(gA, w.w, aA.w);                 \
    aB.x = fmaf(gB, w.x, aB.x); aB.y = fmaf(gB, w.y, aB.y);                 \
    aB.z = fmaf(gB, w.z, aB.z); aB.w = fmaf(gB, w.w, aB.w);                 \
  }
  // ---- layer 1: A[{k2,k2+16}][0..66] x Wb -> Bf (4 outs/thread/row)
  {
    const int o0 = jj * 4;
    float4 aA = *(const float4*)(bb0 + o0);
    float4 aB = aA;
    const float* AkA = &A[k2 * 76];
    const float* AkB = &A[(k2 + 16) * 76];
    for (int c = 0; c < 64; c += 4) {
      float4 gA = *(const float4*)(AkA + c);
      float4 gB = *(const float4*)(AkB + c);
      FMA4x2(gA.x, gB.x, Wb + (c + 0) * 64 + o0);
      FMA4x2(gA.y, gB.y, Wb + (c + 1) * 64 + o0);
      FMA4x2(gA.z, gB.z, Wb + (c + 2) * 64 + o0);
      FMA4x2(gA.w, gB.w, Wb + (c + 3) * 64 + o0);
    }
    float4 gA = *(const float4*)(AkA + 64);   // elems 64..66 (+pad 67 unused)
    float4 gB = *(const float4*)(AkB + 64);
    FMA4x2(gA.x, gB.x, Wb + 64 * 64 + o0);
    FMA4x2(gA.y, gB.y, Wb + 65 * 64 + o0);
    FMA4x2(gA.z, gB.z, Wb + 66 * 64 + o0);
    float4 rA; rA.x = fmaxf(aA.x, 0.f); rA.y = fmaxf(aA.y, 0.f);
    rA.z = fmaxf(aA.z, 0.f); rA.w = fmaxf(aA.w, 0.f);
    float4 rB; rB.x = fmaxf(aB.x, 0.f); rB.y = fmaxf(aB.y, 0.f);
    rB.z = fmaxf(aB.z, 0.f); rB.w = fmaxf(aB.w, 0.f);
    *(float4*)&Bf[k2 * 76 + o0] = rA;
    *(float4*)&Bf[(k2 + 16) * 76 + o0] = rB;
  }
  __syncthreads();
  // ---- stage W1 (64*64 = 4096 floats = 1024 float4)
  {
    const float4* src = (const float4*)wT1;
    float4* dst = (float4*)Wb;
    for (int i = tid; i < 1024; i += 256) dst[i] = src[i];
  }
  __syncthreads();
  // ---- layer 2: Bf[{k2,k2+16}][0..63] x Wb -> A
  {
    const int o0 = jj * 4;
    float4 aA = *(const float4*)(bb1 + o0);
    float4 aB = aA;
    const float* BkA = &Bf[k2 * 76];
    const float* BkB = &Bf[(k2 + 16) * 76];
    for (int c = 0; c < 64; c += 4) {
      float4 gA = *(const float4*)(BkA + c);
      float4 gB = *(const float4*)(BkB + c);
      FMA4x2(gA.x, gB.x, Wb + (c + 0) * 64 + o0);
      FMA4x2(gA.y, gB.y, Wb + (c + 1) * 64 + o0);
      FMA4x2(gA.z, gB.z, Wb + (c + 2) * 64 + o0);
      FMA4x2(gA.w, gB.w, Wb + (c + 3) * 64 + o0);
    }
    float4 rA; rA.x = fmaxf(aA.x, 0.f); rA.y = fmaxf(aA.y, 0.f);
    rA.z = fmaxf(aA.z, 0.f); rA.w = fmaxf(aA.w, 0.f);
    float4 rB; rB.x = fmaxf(aB.x, 0.f); rB.y = fmaxf(aB.y, 0.f);
    rB.z = fmaxf(aB.z, 0.f); rB.w = fmaxf(aB.w, 0.f);
    *(float4*)&A[k2 * 76 + o0] = rA;
    *(float4*)&A[(k2 + 16) * 76 + o0] = rB;
  }
  __syncthreads();
  // ---- stage W2 (64*128 = 8192 floats = 2048 float4)
  {
    const float4* src = (const float4*)wT2;
    float4* dst = (float4*)Wb;
    for (int i = tid; i < 2048; i += 256) dst[i] = src[i];
  }
  __syncthreads();
  // ---- layer 3: A[{k2,k2+16}][0..63] x Wb -> Cf (8 outs/thread/row; no relu)
  {
    const int t0 = jj * 8;
    float4 aA0 = *(const float4*)(bb2 + t0);
    float4 aA1 = *(const float4*)(bb2 + t0 + 4);
    float4 aB0 = aA0, aB1 = aA1;
    const float* AkA = &A[k2 * 76];
    const float* AkB = &A[(k2 + 16) * 76];
#define FMA8x2(gA, gB, base)                                                \
    {                                                                       \
      float4 w0v = *(const float4*)(base);                                  \
      float4 w1v = *(const float4*)((base) + 4);                            \
      aA0.x = fmaf(gA, w0v.x, aA0.x); aA0.y = fmaf(gA, w0v.y, aA0.y);       \
      aA0.z = fmaf(gA, w0v.z, aA0.z); aA0.w = fmaf(gA, w0v.w, aA0.w);       \
      aA1.x = fmaf(gA, w1v.x, aA1.x); aA1.y = fmaf(gA, w1v.y, aA1.y);       \
      aA1.z = fmaf(gA, w1v.z, aA1.z); aA1.w = fmaf(gA, w1v.w, aA1.w);       \
      aB0.x = fmaf(gB, w0v.x, aB0.x); aB0.y = fmaf(gB, w0v.y, aB0.y);       \
      aB0.z = fmaf(gB, w0v.z, aB0.z); aB0.w = fmaf(gB, w0v.w, aB0.w);       \
      aB1.x = fmaf(gB, w1v.x, aB1.x); aB1.y = fmaf(gB, w1v.y, aB1.y);       \
      aB1.z = fmaf(gB, w1v.z, aB1.z); aB1.w = fmaf(gB, w1v.w, aB1.w);       \
    }
    for (int c = 0; c < 64; c += 4) {
      float4 gA = *(const float4*)(AkA + c);
      float4 gB = *(const float4*)(AkB + c);
      FMA8x2(gA.x, gB.x, Wb + (c + 0) * 128 + t0);
      FMA8x2(gA.y, gB.y, Wb + (c + 1) * 128 + t0);
      FMA8x2(gA.z, gB.z, Wb + (c + 2) * 128 + t0);
      FMA8x2(gA.w, gB.w, Wb + (c + 3) * 128 + t0);
    }
    float* oA = &Cf[k2 * 132 + t0];
    *(float4*)(oA + 0) = aA0;
    *(float4*)(oA + 4) = aA1;
    float* oB = &Cf[(k2 + 16) * 132 + t0];
    *(float4*)(oB + 0) = aB0;
    *(float4*)(oB + 4) = aB1;
  }
  __syncthreads();
  // ---- max over k, relu, store
  if (tid < 128) {
    float m = Cf[tid];
    for (int kk = 1; kk < 32; ++kk) m = fmaxf(m, Cf[kk * 132 + tid]);
    out[(size_t)(NB * NS * 3) + (size_t)q * 128 + tid] = fmaxf(m, 0.0f);
  }
}

extern "C" void kernel_launch(void* const* d_in, const int* in_sizes, int n_in,
                              void* d_out, int out_size, void* d_ws, size_t ws_size,
                              hipStream_t stream)
{
  (void)in_sizes; (void)n_in; (void)out_size; (void)ws_size;
  const float* xyz  = (const float*)d_in[0];
  const float* feat = (const float*)d_in[1];
  const float* w0 = (const float*)d_in[2];
  const float* b0 = (const float*)d_in[3];
  const float* g0 = (const float*)d_in[4];
  const float* be0 = (const float*)d_in[5];
  const float* m0 = (const float*)d_in[6];
  const float* v0 = (const float*)d_in[7];
  const float* w1 = (const float*)d_in[8];
  const float* b1 = (const float*)d_in[9];
  const float* g1 = (const float*)d_in[10];
  const float* be1 = (const float*)d_in[11];
  const float* m1 = (const float*)d_in[12];
  const float* v1 = (const float*)d_in[13];
  const float* w2 = (const float*)d_in[14];
  const float* b2 = (const float*)d_in[15];
  const float* g2 = (const float*)d_in[16];
  const float* be2 = (const float*)d_in[17];
  const float* m2 = (const float*)d_in[18];
  const float* v2 = (const float*)d_in[19];

  float* ws = (float*)d_ws;
  int* fpsi = (int*)(ws + WS_FPSIDX);
  float4* pack = (float4*)(ws + WS_PACK);
  int* gidx = (int*)(ws + WS_GIDX);
  float* wT0 = ws + WS_WT0; float* bb0 = ws + WS_BB0;
  float* wT1 = ws + WS_WT1; float* bb1 = ws + WS_BB1;
  float* wT2 = ws + WS_WT2; float* bb2 = ws + WS_BB2;
  float* nxyz = (float*)d_out;

  hipLaunchKernelGGL(prep_pack, dim3((NB * NN + 255) / 256), dim3(256), 0, stream,
                     xyz, pack);
  hipLaunchKernelGGL(prep_w, dim3(66), dim3(256), 0, stream,
                     w0, b0, g0, be0, m0, v0,
                     w1, b1, g1, be1, m1, v1,
                     w2, b2, g2, be2, m2, v2,
                     wT0, bb0, wT1, bb1, wT2, bb2);
  hipLaunchKernelGGL(fps_kernel, dim3(NB), dim3(1024), 0, stream,
                     xyz, fpsi, nxyz);
  hipLaunchKernelGGL(ballq_kernel, dim3(NB * NS / 4), dim3(256), 0, stream,
                     pack, fpsi, gidx);
  hipLaunchKernelGGL(mlp_kernel, dim3(NB * NS), dim3(256), 0, stream,
                     xyz, feat, gidx, nxyz,
                     wT0, bb0, wT1, bb1, wT2, bb2, (float*)d_out);
}

// Round 16
// 1827.899 us; speedup vs baseline: 1.0865x; 1.0865x over previous
//
#include <hip/hip_runtime.h>

#define NB 4
#define NN 8192
#define NS 2048
#define NK 32
#define NCF 64
#define R2 0.04f

// ws layout in float units
#define WS_FPSIDX 0              // int[NB*NS]           = 8192
#define WS_PACK   8192           // float4[NB*NN]        = 131072 floats
#define WS_GIDX   139264         // int[NB*NS*NK]        = 262144
#define WS_WT0    401408         // 67*64
#define WS_BB0    405696         // 64
#define WS_WT1    405760         // 64*64
#define WS_BB1    409856         // 64
#define WS_WT2    409920         // 64*128
#define WS_BB2    418112         // 128

__device__ __forceinline__ unsigned long long umax64(unsigned long long a,
                                                     unsigned long long b) {
  return a > b ? a : b;   // v_cmp_lt_u64 + cndmask pair
}

template <int CTRL>
__device__ __forceinline__ void dpp_max64(unsigned& kl, unsigned& kh) {
  // 64-bit max ladder step: bound_ctrl=true -> shifted-in lanes see key=0,
  // which never wins (real keys have kl = ~idx > 0).
  unsigned nl = (unsigned)__builtin_amdgcn_update_dpp(0, (int)kl, CTRL, 0xf, 0xf, true);
  unsigned nh = (unsigned)__builtin_amdgcn_update_dpp(0, (int)kh, CTRL, 0xf, 0xf, true);
  unsigned long long cur = ((unsigned long long)kh << 32) | kl;
  unsigned long long oth = ((unsigned long long)nh << 32) | nl;
  bool take = oth > cur;
  kl = take ? nl : kl;
  kh = take ? nh : kh;
}

template <int CTRL>
__device__ __forceinline__ float dpp_fmin2(float x) {
  // bound_ctrl=false + old=x: invalid lanes contribute x itself (idempotent).
  int t = __builtin_amdgcn_update_dpp(__float_as_int(x), __float_as_int(x),
                                      CTRL, 0xf, 0xf, false);
  return fminf(x, __int_as_float(t));
}
template <int CTRL>
__device__ __forceinline__ float dpp_fmax2(float x) {
  int t = __builtin_amdgcn_update_dpp(__float_as_int(x), __float_as_int(x),
                                      CTRL, 0xf, 0xf, false);
  return fmaxf(x, __int_as_float(t));
}
__device__ __forceinline__ float wave_min_bcast(float x) {
  x = dpp_fmin2<0x111>(x); x = dpp_fmin2<0x112>(x); x = dpp_fmin2<0x114>(x);
  x = dpp_fmin2<0x118>(x); x = dpp_fmin2<0x142>(x); x = dpp_fmin2<0x143>(x);
  return __int_as_float(__builtin_amdgcn_readlane(__float_as_int(x), 63));
}
__device__ __forceinline__ float wave_max_bcast(float x) {
  x = dpp_fmax2<0x111>(x); x = dpp_fmax2<0x112>(x); x = dpp_fmax2<0x114>(x);
  x = dpp_fmax2<0x118>(x); x = dpp_fmax2<0x142>(x); x = dpp_fmax2<0x143>(x);
  return __int_as_float(__builtin_amdgcn_readlane(__float_as_int(x), 63));
}

__device__ __forceinline__ int morton12(int ix, int iy, int iz) {
  // 4 bits each (16^3 grid), interleaved: bit k -> bit 3k.
  auto sp = [](int v) {
    return (v & 1) | ((v & 2) << 2) | ((v & 4) << 4) | ((v & 8) << 6);
  };
  return sp(ix) | (sp(iy) << 1) | (sp(iz) << 2);
}

// ---------------------------------------------------------------------------
// FPS (R13 structure, best measured 1584 us -- R15's scattered coord
// prefetch REVERTED: it caused 1.1M LDS bank conflicts vs 23K): one block
// per batch, 1024 threads (16 waves), 8 points/thread.
// Exact semantics preserved: dist init 1e10f, far0=0,
// d = ((dx*dx+dy*dy)+dz*dz) with NO fma contraction; dist=min(dist,d);
// argmax first-index tiebreak via u64 keys (distbits<<32 | ~idx).
// 16^3 Morton-binned waves own compact 512-pt runs with exact float
// register bboxes; a wave updates only if lb(bbox,c)^2*0.999 < cachedmax
// (skip is provably a no-op; cached key republished -> bit-identical).
// Center coords via ONE same-address broadcast LDS read (conflict-free).
// ---------------------------------------------------------------------------
__global__ __launch_bounds__(1024)
void fps_kernel(const float* __restrict__ xyz, int* __restrict__ fps_idx,
                float* __restrict__ new_xyz)
{
#pragma clang fp contract(off)
  const int b = blockIdx.x;
  const int tid = threadIdx.x;
  const int lane = tid & 63;
  const int wid = tid >> 6;
  const float* __restrict__ P = xyz + (size_t)b * (NN * 3);

  __shared__ float Pl[NN * 3];                 // 96 KB staged coords
  __shared__ unsigned short sidx[NN];          // 16 KB binned orig indices
  __shared__ int hist[4096];                   // 16 KB fine-cell histogram
  __shared__ int hsum[64];                     // chunk partial sums (scan)
  __shared__ unsigned long long skey[2][16];   // double-buffered wave keys

  // ---- one-time: stage coords, Morton-bin (16^3), scatter ----
  {
    const float4* __restrict__ src = (const float4*)P;
    float4* dst = (float4*)Pl;
#pragma unroll
    for (int i = 0; i < 6; ++i) dst[tid + i * 1024] = src[tid + i * 1024];
  }
#pragma unroll
  for (int i = 0; i < 4; ++i) hist[tid + i * 1024] = 0;
  __syncthreads();

  unsigned short mycell[8];
#pragma unroll
  for (int j = 0; j < 8; ++j) {
    int p = tid + j * 1024;
    float x = Pl[p * 3 + 0], y = Pl[p * 3 + 1], z = Pl[p * 3 + 2];
    int ix = min(15, max(0, (int)(x * 16.0f)));
    int iy = min(15, max(0, (int)(y * 16.0f)));
    int iz = min(15, max(0, (int)(z * 16.0f)));
    int cell = morton12(ix, iy, iz);
    mycell[j] = (unsigned short)cell;
    atomicAdd(&hist[cell], 1);
  }
  __syncthreads();
  // ---- 3-phase exclusive prefix over 4096 cells (one-time) ----
  if (tid < 64) {      // phase A: local scan within 64-cell chunk
    int acc = 0;
    for (int c = 0; c < 64; ++c) {
      int h = hist[tid * 64 + c];
      hist[tid * 64 + c] = acc;
      acc += h;
    }
    hsum[tid] = acc;
  }
  __syncthreads();
  if (tid == 0) {      // phase B: scan the 64 chunk totals
    int acc = 0;
    for (int c = 0; c < 64; ++c) { int h = hsum[c]; hsum[c] = acc; acc += h; }
  }
  __syncthreads();
#pragma unroll
  for (int i = 0; i < 4; ++i) {  // phase C: add chunk offsets
    int c = tid + i * 1024;
    hist[c] += hsum[c >> 6];
  }
  __syncthreads();
#pragma unroll
  for (int j = 0; j < 8; ++j) {
    int p = tid + j * 1024;
    int pos = atomicAdd(&hist[mycell[j]], 1);
    sidx[pos] = (unsigned short)p;
  }
  __syncthreads();

  // ---- load my 8 binned points + keys; wave slots are contiguous 512 ----
  float px[8], py[8], pz[8], dist[8];
  unsigned klc[8];
#pragma unroll
  for (int j = 0; j < 8; ++j) {
    int slot = wid * 512 + j * 64 + lane;
    int p = sidx[slot];
    px[j] = Pl[p * 3 + 0];
    py[j] = Pl[p * 3 + 1];
    pz[j] = Pl[p * 3 + 2];
    dist[j] = 1e10f;
    klc[j] = 0xFFFFFFFFu - (unsigned)p;   // ~orig idx: bigger == smaller index
  }
  // ---- wave bbox (registers, broadcast via readlane) ----
  float mnx = fminf(fminf(fminf(px[0], px[1]), fminf(px[2], px[3])),
                    fminf(fminf(px[4], px[5]), fminf(px[6], px[7])));
  float mxx = fmaxf(fmaxf(fmaxf(px[0], px[1]), fmaxf(px[2], px[3])),
                    fmaxf(fmaxf(px[4], px[5]), fmaxf(px[6], px[7])));
  float mny = fminf(fminf(fminf(py[0], py[1]), fminf(py[2], py[3])),
                    fminf(fminf(py[4], py[5]), fminf(py[6], py[7])));
  float mxy = fmaxf(fmaxf(fmaxf(py[0], py[1]), fmaxf(py[2], py[3])),
                    fmaxf(fmaxf(py[4], py[5]), fmaxf(py[6], py[7])));
  float mnz = fminf(fminf(fminf(pz[0], pz[1]), fminf(pz[2], pz[3])),
                    fminf(fminf(pz[4], pz[5]), fminf(pz[6], pz[7])));
  float mxz = fmaxf(fmaxf(fmaxf(pz[0], pz[1]), fmaxf(pz[2], pz[3])),
                    fmaxf(fmaxf(pz[4], pz[5]), fmaxf(pz[6], pz[7])));
  const float blx = wave_min_bcast(mnx), bhx = wave_max_bcast(mxx);
  const float bly = wave_min_bcast(mny), bhy = wave_max_bcast(mxy);
  const float blz = wave_min_bcast(mnz), bhz = wave_max_bcast(mxz);

  float cx = P[0], cy = P[1], cz = P[2];   // first center = point 0
  int far = 0;
  unsigned ckl = 0u, ckh = 0u;             // cached wave key (lane 63 holds it)
  float cachedmax = 1e10f;                 // forces update at k=0

  for (int k = 0; k < NS; ++k) {
    if (tid == 0) {
      fps_idx[b * NS + k] = far;
      float* o = new_xyz + ((size_t)b * NS + k) * 3;
      o[0] = cx; o[1] = cy; o[2] = cz;
    }
    if (k == NS - 1) break;

    // ---- bbox pruning test (wave-uniform; skip is provably a no-op) ----
    float dlx = fmaxf(fmaxf(blx - cx, cx - bhx), 0.0f);
    float dly = fmaxf(fmaxf(bly - cy, cy - bhy), 0.0f);
    float dlz = fmaxf(fmaxf(blz - cz, cz - bhz), 0.0f);
    float dlb = dlx * dlx + dly * dly + dlz * dlz;
    int doupd = __builtin_amdgcn_readfirstlane(
        (int)!(dlb * 0.999f >= cachedmax));
    if (doupd) {
      // ---- distance update (exact math) + u64 key build
      unsigned long long k8[8];
#pragma unroll
      for (int j = 0; j < 8; ++j) {
        float dx = px[j] - cx;
        float dy = py[j] - cy;
        float dz = pz[j] - cz;
        float d = (dx * dx + dy * dy) + dz * dz;   // plain mul/add, l-to-r
        float t = fminf(dist[j], d);
        dist[j] = t;
        k8[j] = ((unsigned long long)(unsigned)__float_as_int(t) << 32) | klc[j];
      }
      unsigned long long t0 = umax64(k8[0], k8[1]);
      unsigned long long t1 = umax64(k8[2], k8[3]);
      unsigned long long t2 = umax64(k8[4], k8[5]);
      unsigned long long t3 = umax64(k8[6], k8[7]);
      unsigned long long bk = umax64(umax64(t0, t1), umax64(t2, t3));

      unsigned kl = (unsigned)bk, kh = (unsigned)(bk >> 32);
      dpp_max64<0x111>(kl, kh);
      dpp_max64<0x112>(kl, kh);
      dpp_max64<0x114>(kl, kh);
      dpp_max64<0x118>(kl, kh);
      dpp_max64<0x142>(kl, kh);
      dpp_max64<0x143>(kl, kh);
      ckl = kl; ckh = kh;
      cachedmax = __int_as_float(__builtin_amdgcn_readlane((int)kh, 63));
    }

    const int ws = k & 1;
    if (lane == 63) {
      skey[ws][wid] = ((unsigned long long)ckh << 32) | ckl;
    }
    __syncthreads();

    // ---- cross-wave reduce over 16 u64 keys (conflict-free b64 reads)
    unsigned long long sk = skey[ws][lane & 15];
    unsigned skl = (unsigned)sk, skh = (unsigned)(sk >> 32);
    dpp_max64<0x111>(skl, skh);
    dpp_max64<0x112>(skl, skh);
    dpp_max64<0x114>(skl, skh);
    dpp_max64<0x118>(skl, skh);  // lane15 of each row = block max
    unsigned kl15 = (unsigned)__builtin_amdgcn_readlane((int)skl, 15);
    far = (int)(0xFFFFFFFFu - kl15);

    // ---- center coords: one same-address broadcast LDS read (all waves)
    const float* cp = Pl + far * 3;
    cx = cp[0]; cy = cp[1]; cz = cp[2];
  }
}

// ---------------------------------------------------------------------------
// pack = {x, y, z, (x*x+y*y)+z*z} per point (sq matches jnp.sum(xyz**2,-1))
// ---------------------------------------------------------------------------
__global__ void prep_pack(const float* __restrict__ xyz, float4* __restrict__ pack)
{
#pragma clang fp contract(off)
  int t = blockIdx.x * 256 + threadIdx.x;
  if (t < NB * NN) {
    float x = xyz[t * 3 + 0], y = xyz[t * 3 + 1], z = xyz[t * 3 + 2];
    float4 v; v.x = x; v.y = y; v.z = z; v.w = (x * x + y * y) + z * z;
    pack[t] = v;
  }
}

// ---------------------------------------------------------------------------
// Fold BN into weights, transpose to (c,o), remap layer0 channels so that
// c'=0..63 are features (orig 3..66) and c'=64..66 are rel-xyz (orig 0..2).
// ---------------------------------------------------------------------------
__global__ void prep_w(
    const float* __restrict__ w0, const float* __restrict__ b0,
    const float* __restrict__ g0, const float* __restrict__ be0,
    const float* __restrict__ m0, const float* __restrict__ v0,
    const float* __restrict__ w1, const float* __restrict__ b1,
    const float* __restrict__ g1, const float* __restrict__ be1,
    const float* __restrict__ m1, const float* __restrict__ v1,
    const float* __restrict__ w2, const float* __restrict__ b2,
    const float* __restrict__ g2, const float* __restrict__ be2,
    const float* __restrict__ m2, const float* __restrict__ v2,
    float* __restrict__ wT0, float* __restrict__ bb0,
    float* __restrict__ wT1, float* __restrict__ bb1,
    float* __restrict__ wT2, float* __restrict__ bb2)
{
  int t = blockIdx.x * 256 + threadIdx.x;
  if (t < 4288) {
    int c = t >> 6, o = t & 63;
    int oc = (c < 64) ? (c + 3) : (c - 64);
    float sc = g0[o] * rsqrtf(v0[o] + 1e-5f);
    wT0[t] = w0[o * 67 + oc] * sc;
  } else if (t < 4352) {
    int o = t - 4288;
    float sc = g0[o] * rsqrtf(v0[o] + 1e-5f);
    bb0[o] = (b0[o] - m0[o]) * sc + be0[o];
  } else if (t < 8448) {
    int u = t - 4352;
    int c = u >> 6, o = u & 63;
    float sc = g1[o] * rsqrtf(v1[o] + 1e-5f);
    wT1[u] = w1[o * 64 + c] * sc;
  } else if (t < 8512) {
    int o = t - 8448;
    float sc = g1[o] * rsqrtf(v1[o] + 1e-5f);
    bb1[o] = (b1[o] - m1[o]) * sc + be1[o];
  } else if (t < 16704) {
    int u = t - 8512;
    int c = u >> 7, o = u & 127;
    float sc = g2[o] * rsqrtf(v2[o] + 1e-5f);
    wT2[u] = w2[o * 64 + c] * sc;
  } else if (t < 16832) {
    int o = t - 16704;
    float sc = g2[o] * rsqrtf(v2[o] + 1e-5f);
    bb2[o] = (b2[o] - m2[o]) * sc + be2[o];
  }
}

// ---------------------------------------------------------------------------
// Ball query: one wave per query point. sqr = (sq_q + sq_x) - 2*dot with
// dot as Eigen-style fma chain over (x,y,z). Packed {x,y,z,sq} float4 loads
// (1 dwordx4/point). First 32 in-ball indices ascending; pad with first hit.
// ---------------------------------------------------------------------------
__global__ __launch_bounds__(256)
void ballq_kernel(const float4* __restrict__ pack,
                  const int* __restrict__ fps_idx, int* __restrict__ gidx)
{
#pragma clang fp contract(off)
  const int lane = threadIdx.x & 63;
  const int q = blockIdx.x * 4 + (threadIdx.x >> 6);
  const int b = q >> 11;
  const int s = q & 2047;
  const float4* __restrict__ PK = pack + (size_t)b * NN;
  const int cidx = fps_idx[b * NS + s];
  const float4 c4 = PK[cidx];
  const float cx = c4.x, cy = c4.y, cz = c4.z, csq = c4.w;
  int* __restrict__ g = gidx + (size_t)q * NK;
  int cnt = 0, firstn = 0;
  bool havefirst = false;
  for (int n0 = 0; n0 < NN; n0 += 64) {
    int n = n0 + lane;
    float4 p4 = PK[n];
    float dot = p4.x * cx;         // first gebp step: fma(a0,b0,0) == rn(a0*b0)
    dot = fmaf(p4.y, cy, dot);
    dot = fmaf(p4.z, cz, dot);
    float sqr = (csq + p4.w) - 2.0f * dot;
    bool in_ = (sqr <= R2);
    unsigned long long m = __ballot(in_);
    if (!havefirst && m) { firstn = n0 + __builtin_ctzll(m); havefirst = true; }
    int pos = cnt + __popcll(m & ((1ull << lane) - 1ull));
    if (in_ && pos < NK) g[pos] = n;
    cnt += __popcll(m);
    if (cnt >= NK) break;
  }
  if (cnt < NK && lane < NK - cnt) g[cnt + lane] = firstn;
}

// ---------------------------------------------------------------------------
// Grouped MLP + k-max: one block (256 thr) per query. Activations in LDS;
// weights staged per layer into one reused 32KB LDS buffer (R12 win).
// 2-row register blocking (R15 win): thread (k2,jj) computes rows k2 and
// k2+16, so every weight b128 read feeds TWO activation rows. Per-output
// accumulation order unchanged (c ascending) -> bit-identical. ReLU of
// layer 3 deferred past the max (relu(max) == max(relu)).
// ---------------------------------------------------------------------------
__global__ __launch_bounds__(256)
void mlp_kernel(const float* __restrict__ xyz, const float* __restrict__ feat,
                const int* __restrict__ gidx, const float* __restrict__ nxyz,
                const float* __restrict__ wT0, const float* __restrict__ bb0,
                const float* __restrict__ wT1, const float* __restrict__ bb1,
                const float* __restrict__ wT2, const float* __restrict__ bb2,
                float* __restrict__ out)
{
  const int q = blockIdx.x;
  const int b = q >> 11;
  const int tid = threadIdx.x;
  __shared__ int sg[32];
  __shared__ float A[32 * 76];    // stride 76 (=19*4): 16B-aligned rows
  __shared__ float Bf[32 * 76];
  __shared__ float Cf[32 * 132];
  __shared__ float Wb[8192];      // 32KB reused weight buffer (max 64*128)
  if (tid < 32) sg[tid] = gidx[(size_t)q * NK + tid];
  __syncthreads();
  {
    const int k = tid >> 3, j = tid & 7;
    const int p = sg[k];
    const float* fp = feat + ((size_t)b * NN + p) * NCF + j * 8;
    float4 f0 = *(const float4*)fp;
    float4 f1 = *(const float4*)(fp + 4);
    float* a = &A[k * 76 + j * 8];
    *(float4*)a = f0;
    *(float4*)(a + 4) = f1;
    if (j == 0) {
      float cx = nxyz[(size_t)q * 3 + 0];
      float cy = nxyz[(size_t)q * 3 + 1];
      float cz = nxyz[(size_t)q * 3 + 2];
      const float* pp = xyz + ((size_t)b * NN + p) * 3;
      A[k * 76 + 64] = pp[0] - cx;
      A[k * 76 + 65] = pp[1] - cy;
      A[k * 76 + 66] = pp[2] - cz;
    }
  }
  // ---- stage W0 (67*64 = 4288 floats = 1072 float4)
  {
    const float4* src = (const float4*)wT0;
    float4* dst = (float4*)Wb;
    for (int i = tid; i < 1072; i += 256) dst[i] = src[i];
  }
  __syncthreads();

  const int k2 = tid >> 4;       // row pair: k2 and k2+16
  const int jj = tid & 15;
#define FMA4x2(gA, gB, base)                                                \
  {                                                                         \
    float4 w = *(const float4*)(base);                                      \
    aA.x = fmaf(gA, w.x, aA.x); aA.y = fmaf(gA, w.y, aA.y);                 \
    aA.z = fmaf(gA, w.z, aA.z); aA.w = fmaf(gA, w.w, aA.w);                 \
    aB.x = fmaf(gB, w.x, aB.x); aB.y = fmaf(gB, w.y, aB.y);                 \
    aB.z = fmaf(gB, w.z, aB.z); aB.w = fmaf(gB, w.w, aB.w);                 \
  }
  // ---- layer 1: A[{k2,k2+16}][0..66] x Wb -> Bf (4 outs/thread/row)
  {
    const int o0 = jj * 4;
    float4 aA = *(const float4*)(bb0 + o0);
    float4 aB = aA;
    const float* AkA = &A[k2 * 76];
    const float* AkB = &A[(k2 + 16) * 76];
    for (int c = 0; c < 64; c += 4) {
      float4 gA = *(const float4*)(AkA + c);
      float4 gB = *(const float4*)(AkB + c);
      FMA4x2(gA.x, gB.x, Wb + (c + 0) * 64 + o0);
      FMA4x2(gA.y, gB.y, Wb + (c + 1) * 64 + o0);
      FMA4x2(gA.z, gB.z, Wb + (c + 2) * 64 + o0);
      FMA4x2(gA.w, gB.w, Wb + (c + 3) * 64 + o0);
    }
    float4 gA = *(const float4*)(AkA + 64);   // elems 64..66 (+pad 67 unused)
    float4 gB = *(const float4*)(AkB + 64);
    FMA4x2(gA.x, gB.x, Wb + 64 * 64 + o0);
    FMA4x2(gA.y, gB.y, Wb + 65 * 64 + o0);
    FMA4x2(gA.z, gB.z, Wb + 66 * 64 + o0);
    float4 rA; rA.x = fmaxf(aA.x, 0.f); rA.y = fmaxf(aA.y, 0.f);
    rA.z = fmaxf(aA.z, 0.f); rA.w = fmaxf(aA.w, 0.f);
    float4 rB; rB.x = fmaxf(aB.x, 0.f); rB.y = fmaxf(aB.y, 0.f);
    rB.z = fmaxf(aB.z, 0.f); rB.w = fmaxf(aB.w, 0.f);
    *(float4*)&Bf[k2 * 76 + o0] = rA;
    *(float4*)&Bf[(k2 + 16) * 76 + o0] = rB;
  }
  __syncthreads();
  // ---- stage W1 (64*64 = 4096 floats = 1024 float4)
  {
    const float4* src = (const float4*)wT1;
    float4* dst = (float4*)Wb;
    for (int i = tid; i < 1024; i += 256) dst[i] = src[i];
  }
  __syncthreads();
  // ---- layer 2: Bf[{k2,k2+16}][0..63] x Wb -> A
  {
    const int o0 = jj * 4;
    float4 aA = *(const float4*)(bb1 + o0);
    float4 aB = aA;
    const float* BkA = &Bf[k2 * 76];
    const float* BkB = &Bf[(k2 + 16) * 76];
    for (int c = 0; c < 64; c += 4) {
      float4 gA = *(const float4*)(BkA + c);
      float4 gB = *(const float4*)(BkB + c);
      FMA4x2(gA.x, gB.x, Wb + (c + 0) * 64 + o0);
      FMA4x2(gA.y, gB.y, Wb + (c + 1) * 64 + o0);
      FMA4x2(gA.z, gB.z, Wb + (c + 2) * 64 + o0);
      FMA4x2(gA.w, gB.w, Wb + (c + 3) * 64 + o0);
    }
    float4 rA; rA.x = fmaxf(aA.x, 0.f); rA.y = fmaxf(aA.y, 0.f);
    rA.z = fmaxf(aA.z, 0.f); rA.w = fmaxf(aA.w, 0.f);
    float4 rB; rB.x = fmaxf(aB.x, 0.f); rB.y = fmaxf(aB.y, 0.f);
    rB.z = fmaxf(aB.z, 0.f); rB.w = fmaxf(aB.w, 0.f);
    *(float4*)&A[k2 * 76 + o0] = rA;
    *(float4*)&A[(k2 + 16) * 76 + o0] = rB;
  }
  __syncthreads();
  // ---- stage W2 (64*128 = 8192 floats = 2048 float4)
  {
    const float4* src = (const float4*)wT2;
    float4* dst = (float4*)Wb;
    for (int i = tid; i < 2048; i += 256) dst[i] = src[i];
  }
  __syncthreads();
  // ---- layer 3: A[{k2,k2+16}][0..63] x Wb -> Cf (8 outs/thread/row; no relu)
  {
    const int t0 = jj * 8;
    float4 aA0 = *(const float4*)(bb2 + t0);
    float4 aA1 = *(const float4*)(bb2 + t0 + 4);
    float4 aB0 = aA0, aB1 = aA1;
    const float* AkA = &A[k2 * 76];
    const float* AkB = &A[(k2 + 16) * 76];
#define FMA8x2(gA, gB, base)                                                \
    {                                                                       \
      float4 w0v = *(const float4*)(base);                                  \
      float4 w1v = *(const float4*)((base) + 4);                            \
      aA0.x = fmaf(gA, w0v.x, aA0.x); aA0.y = fmaf(gA, w0v.y, aA0.y);       \
      aA0.z = fmaf(gA, w0v.z, aA0.z); aA0.w = fmaf(gA, w0v.w, aA0.w);       \
      aA1.x = fmaf(gA, w1v.x, aA1.x); aA1.y = fmaf(gA, w1v.y, aA1.y);       \
      aA1.z = fmaf(gA, w1v.z, aA1.z); aA1.w = fmaf(gA, w1v.w, aA1.w);       \
      aB0.x = fmaf(gB, w0v.x, aB0.x); aB0.y = fmaf(gB, w0v.y, aB0.y);       \
      aB0.z = fmaf(gB, w0v.z, aB0.z); aB0.w = fmaf(gB, w0v.w, aB0.w);       \
      aB1.x = fmaf(gB, w1v.x, aB1.x); aB1.y = fmaf(gB, w1v.y, aB1.y);       \
      aB1.z = fmaf(gB, w1v.z, aB1.z); aB1.w = fmaf(gB, w1v.w, aB1.w);       \
    }
    for (int c = 0; c < 64; c += 4) {
      float4 gA = *(const float4*)(AkA + c);
      float4 gB = *(const float4*)(AkB + c);
      FMA8x2(gA.x, gB.x, Wb + (c + 0) * 128 + t0);
      FMA8x2(gA.y, gB.y, Wb + (c + 1) * 128 + t0);
      FMA8x2(gA.z, gB.z, Wb + (c + 2) * 128 + t0);
      FMA8x2(gA.w, gB.w, Wb + (c + 3) * 128 + t0);
    }
    float* oA = &Cf[k2 * 132 + t0];
    *(float4*)(oA + 0) = aA0;
    *(float4*)(oA + 4) = aA1;
    float* oB = &Cf[(k2 + 16) * 132 + t0];
    *(float4*)(oB + 0) = aB0;
    *(float4*)(oB + 4) = aB1;
  }
  __syncthreads();
  // ---- max over k, relu, store
  if (tid < 128) {
    float m = Cf[tid];
    for (int kk = 1; kk < 32; ++kk) m = fmaxf(m, Cf[kk * 132 + tid]);
    out[(size_t)(NB * NS * 3) + (size_t)q * 128 + tid] = fmaxf(m, 0.0f);
  }
}

extern "C" void kernel_launch(void* const* d_in, const int* in_sizes, int n_in,
                              void* d_out, int out_size, void* d_ws, size_t ws_size,
                              hipStream_t stream)
{
  (void)in_sizes; (void)n_in; (void)out_size; (void)ws_size;
  const float* xyz  = (const float*)d_in[0];
  const float* feat = (const float*)d_in[1];
  const float* w0 = (const float*)d_in[2];
  const float* b0 = (const float*)d_in[3];
  const float* g0 = (const float*)d_in[4];
  const float* be0 = (const float*)d_in[5];
  const float* m0 = (const float*)d_in[6];
  const float* v0 = (const float*)d_in[7];
  const float* w1 = (const float*)d_in[8];
  const float* b1 = (const float*)d_in[9];
  const float* g1 = (const float*)d_in[10];
  const float* be1 = (const float*)d_in[11];
  const float* m1 = (const float*)d_in[12];
  const float* v1 = (const float*)d_in[13];
  const float* w2 = (const float*)d_in[14];
  const float* b2 = (const float*)d_in[15];
  const float* g2 = (const float*)d_in[16];
  const float* be2 = (const float*)d_in[17];
  const float* m2 = (const float*)d_in[18];
  const float* v2 = (const float*)d_in[19];

  float* ws = (float*)d_ws;
  int* fpsi = (int*)(ws + WS_FPSIDX);
  float4* pack = (float4*)(ws + WS_PACK);
  int* gidx = (int*)(ws + WS_GIDX);
  float* wT0 = ws + WS_WT0; float* bb0 = ws + WS_BB0;
  float* wT1 = ws + WS_WT1; float* bb1 = ws + WS_BB1;
  float* wT2 = ws + WS_WT2; float* bb2 = ws + WS_BB2;
  float* nxyz = (float*)d_out;

  hipLaunchKernelGGL(prep_pack, dim3((NB * NN + 255) / 256), dim3(256), 0, stream,
                     xyz, pack);
  hipLaunchKernelGGL(prep_w, dim3(66), dim3(256), 0, stream,
                     w0, b0, g0, be0, m0, v0,
                     w1, b1, g1, be1, m1, v1,
                     w2, b2, g2, be2, m2, v2,
                     wT0, bb0, wT1, bb1, wT2, bb2);
  hipLaunchKernelGGL(fps_kernel, dim3(NB), dim3(1024), 0, stream,
                     xyz, fpsi, nxyz);
  hipLaunchKernelGGL(ballq_kernel, dim3(NB * NS / 4), dim3(256), 0, stream,
                     pack, fpsi, gidx);
  hipLaunchKernelGGL(mlp_kernel, dim3(NB * NS), dim3(256), 0, stream,
                     xyz, feat, gidx, nxyz,
                     wT0, bb0, wT1, bb1, wT2, bb2, (float*)d_out);
}

// Round 17
// 1759.910 us; speedup vs baseline: 1.1285x; 1.0386x over previous
//
#include <hip/hip_runtime.h>

#define NB 4
#define NN 8192
#define NS 2048
#define NK 32
#define NCF 64
#define R2 0.04f

typedef float f32x2 __attribute__((ext_vector_type(2)));

// ws layout in float units
#define WS_FPSIDX 0              // int[NB*NS]           = 8192
#define WS_PACK   8192           // float4[NB*NN]        = 131072 floats
#define WS_GIDX   139264         // int[NB*NS*NK]        = 262144
#define WS_WT0    401408         // 67*64
#define WS_BB0    405696         // 64
#define WS_WT1    405760         // 64*64
#define WS_BB1    409856         // 64
#define WS_WT2    409920         // 64*128
#define WS_BB2    418112         // 128

__device__ __forceinline__ unsigned long long umax64(unsigned long long a,
                                                     unsigned long long b) {
  return a > b ? a : b;   // v_cmp_lt_u64 + cndmask pair
}

template <int CTRL>
__device__ __forceinline__ void dpp_max64(unsigned& kl, unsigned& kh) {
  // 64-bit max ladder step: bound_ctrl=true -> shifted-in lanes see key=0,
  // which never wins (real keys have kl = ~idx > 0).
  unsigned nl = (unsigned)__builtin_amdgcn_update_dpp(0, (int)kl, CTRL, 0xf, 0xf, true);
  unsigned nh = (unsigned)__builtin_amdgcn_update_dpp(0, (int)kh, CTRL, 0xf, 0xf, true);
  unsigned long long cur = ((unsigned long long)kh << 32) | kl;
  unsigned long long oth = ((unsigned long long)nh << 32) | nl;
  bool take = oth > cur;
  kl = take ? nl : kl;
  kh = take ? nh : kh;
}

template <int CTRL>
__device__ __forceinline__ float dpp_fmin2(float x) {
  // bound_ctrl=false + old=x: invalid lanes contribute x itself (idempotent).
  int t = __builtin_amdgcn_update_dpp(__float_as_int(x), __float_as_int(x),
                                      CTRL, 0xf, 0xf, false);
  return fminf(x, __int_as_float(t));
}
template <int CTRL>
__device__ __forceinline__ float dpp_fmax2(float x) {
  int t = __builtin_amdgcn_update_dpp(__float_as_int(x), __float_as_int(x),
                                      CTRL, 0xf, 0xf, false);
  return fmaxf(x, __int_as_float(t));
}
__device__ __forceinline__ float wave_min_bcast(float x) {
  x = dpp_fmin2<0x111>(x); x = dpp_fmin2<0x112>(x); x = dpp_fmin2<0x114>(x);
  x = dpp_fmin2<0x118>(x); x = dpp_fmin2<0x142>(x); x = dpp_fmin2<0x143>(x);
  return __int_as_float(__builtin_amdgcn_readlane(__float_as_int(x), 63));
}
__device__ __forceinline__ float wave_max_bcast(float x) {
  x = dpp_fmax2<0x111>(x); x = dpp_fmax2<0x112>(x); x = dpp_fmax2<0x114>(x);
  x = dpp_fmax2<0x118>(x); x = dpp_fmax2<0x142>(x); x = dpp_fmax2<0x143>(x);
  return __int_as_float(__builtin_amdgcn_readlane(__float_as_int(x), 63));
}

__device__ __forceinline__ int morton12(int ix, int iy, int iz) {
  // 4 bits each (16^3 grid), interleaved: bit k -> bit 3k.
  auto sp = [](int v) {
    return (v & 1) | ((v & 2) << 2) | ((v & 4) << 4) | ((v & 8) << 6);
  };
  return sp(ix) | (sp(iy) << 1) | (sp(iz) << 2);
}

// ---------------------------------------------------------------------------
// FPS (R13/R16 structure, best measured 1584 us): one block per batch,
// 1024 threads (16 waves), 8 points/thread held as 4x f32x2.
// Exact semantics preserved: dist init 1e10f, far0=0,
// d = ((dx*dx+dy*dy)+dz*dz) with NO fma contraction; dist=min(dist,d);
// argmax first-index tiebreak via u64 keys (distbits<<32 | ~idx).
// R17 change: the update pass uses <2 x float> vector arithmetic so clang
// can emit packed VOP3P (v_pk_mul_f32/v_pk_add_f32) -- two independent
// IEEE f32 ops per instruction, bit-identical results, ~33% fewer update
// issue slots. Falls back to scalarization harmlessly if not supported.
// 16^3 Morton-binned waves own compact 512-pt runs with exact float
// register bboxes; a wave updates only if lb(bbox,c)^2*0.999 < cachedmax
// (skip is provably a no-op; cached key republished -> bit-identical).
// Center coords via ONE same-address broadcast LDS read (conflict-free).
// ---------------------------------------------------------------------------
__global__ __launch_bounds__(1024)
void fps_kernel(const float* __restrict__ xyz, int* __restrict__ fps_idx,
                float* __restrict__ new_xyz)
{
#pragma clang fp contract(off)
  const int b = blockIdx.x;
  const int tid = threadIdx.x;
  const int lane = tid & 63;
  const int wid = tid >> 6;
  const float* __restrict__ P = xyz + (size_t)b * (NN * 3);

  __shared__ float Pl[NN * 3];                 // 96 KB staged coords
  __shared__ unsigned short sidx[NN];          // 16 KB binned orig indices
  __shared__ int hist[4096];                   // 16 KB fine-cell histogram
  __shared__ int hsum[64];                     // chunk partial sums (scan)
  __shared__ unsigned long long skey[2][16];   // double-buffered wave keys

  // ---- one-time: stage coords, Morton-bin (16^3), scatter ----
  {
    const float4* __restrict__ src = (const float4*)P;
    float4* dst = (float4*)Pl;
#pragma unroll
    for (int i = 0; i < 6; ++i) dst[tid + i * 1024] = src[tid + i * 1024];
  }
#pragma unroll
  for (int i = 0; i < 4; ++i) hist[tid + i * 1024] = 0;
  __syncthreads();

  unsigned short mycell[8];
#pragma unroll
  for (int j = 0; j < 8; ++j) {
    int p = tid + j * 1024;
    float x = Pl[p * 3 + 0], y = Pl[p * 3 + 1], z = Pl[p * 3 + 2];
    int ix = min(15, max(0, (int)(x * 16.0f)));
    int iy = min(15, max(0, (int)(y * 16.0f)));
    int iz = min(15, max(0, (int)(z * 16.0f)));
    int cell = morton12(ix, iy, iz);
    mycell[j] = (unsigned short)cell;
    atomicAdd(&hist[cell], 1);
  }
  __syncthreads();
  // ---- 3-phase exclusive prefix over 4096 cells (one-time) ----
  if (tid < 64) {      // phase A: local scan within 64-cell chunk
    int acc = 0;
    for (int c = 0; c < 64; ++c) {
      int h = hist[tid * 64 + c];
      hist[tid * 64 + c] = acc;
      acc += h;
    }
    hsum[tid] = acc;
  }
  __syncthreads();
  if (tid == 0) {      // phase B: scan the 64 chunk totals
    int acc = 0;
    for (int c = 0; c < 64; ++c) { int h = hsum[c]; hsum[c] = acc; acc += h; }
  }
  __syncthreads();
#pragma unroll
  for (int i = 0; i < 4; ++i) {  // phase C: add chunk offsets
    int c = tid + i * 1024;
    hist[c] += hsum[c >> 6];
  }
  __syncthreads();
#pragma unroll
  for (int j = 0; j < 8; ++j) {
    int p = tid + j * 1024;
    int pos = atomicAdd(&hist[mycell[j]], 1);
    sidx[pos] = (unsigned short)p;
  }
  __syncthreads();

  // ---- load my 8 binned points (4x f32x2) + keys; contiguous 512/wave ----
  f32x2 px2[4], py2[4], pz2[4], dist2[4];
  unsigned klc[8];
  float mnx = 1e30f, mxx = -1e30f, mny = 1e30f, mxy = -1e30f;
  float mnz = 1e30f, mxz = -1e30f;
#pragma unroll
  for (int j = 0; j < 8; ++j) {
    int slot = wid * 512 + j * 64 + lane;
    int p = sidx[slot];
    float x = Pl[p * 3 + 0];
    float y = Pl[p * 3 + 1];
    float z = Pl[p * 3 + 2];
    px2[j >> 1][j & 1] = x;
    py2[j >> 1][j & 1] = y;
    pz2[j >> 1][j & 1] = z;
    dist2[j >> 1][j & 1] = 1e10f;
    klc[j] = 0xFFFFFFFFu - (unsigned)p;   // ~orig idx: bigger == smaller index
    mnx = fminf(mnx, x); mxx = fmaxf(mxx, x);
    mny = fminf(mny, y); mxy = fmaxf(mxy, y);
    mnz = fminf(mnz, z); mxz = fmaxf(mxz, z);
  }
  // ---- wave bbox (registers, broadcast via readlane) ----
  const float blx = wave_min_bcast(mnx), bhx = wave_max_bcast(mxx);
  const float bly = wave_min_bcast(mny), bhy = wave_max_bcast(mxy);
  const float blz = wave_min_bcast(mnz), bhz = wave_max_bcast(mxz);

  float cx = P[0], cy = P[1], cz = P[2];   // first center = point 0
  int far = 0;
  unsigned ckl = 0u, ckh = 0u;             // cached wave key (lane 63 holds it)
  float cachedmax = 1e10f;                 // forces update at k=0

  for (int k = 0; k < NS; ++k) {
    if (tid == 0) {
      fps_idx[b * NS + k] = far;
      float* o = new_xyz + ((size_t)b * NS + k) * 3;
      o[0] = cx; o[1] = cy; o[2] = cz;
    }
    if (k == NS - 1) break;

    // ---- bbox pruning test (wave-uniform; skip is provably a no-op) ----
    float dlx = fmaxf(fmaxf(blx - cx, cx - bhx), 0.0f);
    float dly = fmaxf(fmaxf(bly - cy, cy - bhy), 0.0f);
    float dlz = fmaxf(fmaxf(blz - cz, cz - bhz), 0.0f);
    float dlb = dlx * dlx + dly * dly + dlz * dlz;
    int doupd = __builtin_amdgcn_readfirstlane(
        (int)!(dlb * 0.999f >= cachedmax));
    if (doupd) {
      // ---- distance update (exact math, packed f32 pairs) + u64 key build
      const f32x2 cx2 = {cx, cx}, cy2 = {cy, cy}, cz2 = {cz, cz};
      unsigned long long k8[8];
#pragma unroll
      for (int h = 0; h < 4; ++h) {
        f32x2 dx = px2[h] - cx2;
        f32x2 dy = py2[h] - cy2;
        f32x2 dz = pz2[h] - cz2;
        f32x2 d = (dx * dx + dy * dy) + dz * dz;   // plain pk mul/add, l-to-r
        f32x2 t = __builtin_elementwise_min(dist2[h], d);   // minnum == fminf
        dist2[h] = t;
        k8[2 * h + 0] =
            ((unsigned long long)(unsigned)__float_as_int(t[0]) << 32) |
            klc[2 * h + 0];
        k8[2 * h + 1] =
            ((unsigned long long)(unsigned)__float_as_int(t[1]) << 32) |
            klc[2 * h + 1];
      }
      unsigned long long t0 = umax64(k8[0], k8[1]);
      unsigned long long t1 = umax64(k8[2], k8[3]);
      unsigned long long t2 = umax64(k8[4], k8[5]);
      unsigned long long t3 = umax64(k8[6], k8[7]);
      unsigned long long bk = umax64(umax64(t0, t1), umax64(t2, t3));

      unsigned kl = (unsigned)bk, kh = (unsigned)(bk >> 32);
      dpp_max64<0x111>(kl, kh);
      dpp_max64<0x112>(kl, kh);
      dpp_max64<0x114>(kl, kh);
      dpp_max64<0x118>(kl, kh);
      dpp_max64<0x142>(kl, kh);
      dpp_max64<0x143>(kl, kh);
      ckl = kl; ckh = kh;
      cachedmax = __int_as_float(__builtin_amdgcn_readlane((int)kh, 63));
    }

    const int ws = k & 1;
    if (lane == 63) {
      skey[ws][wid] = ((unsigned long long)ckh << 32) | ckl;
    }
    __syncthreads();

    // ---- cross-wave reduce over 16 u64 keys (conflict-free b64 reads)
    unsigned long long sk = skey[ws][lane & 15];
    unsigned skl = (unsigned)sk, skh = (unsigned)(sk >> 32);
    dpp_max64<0x111>(skl, skh);
    dpp_max64<0x112>(skl, skh);
    dpp_max64<0x114>(skl, skh);
    dpp_max64<0x118>(skl, skh);  // lane15 of each row = block max
    unsigned kl15 = (unsigned)__builtin_amdgcn_readlane((int)skl, 15);
    far = (int)(0xFFFFFFFFu - kl15);

    // ---- center coords: one same-address broadcast LDS read (all waves)
    const float* cp = Pl + far * 3;
    cx = cp[0]; cy = cp[1]; cz = cp[2];
  }
}

// ---------------------------------------------------------------------------
// pack = {x, y, z, (x*x+y*y)+z*z} per point (sq matches jnp.sum(xyz**2,-1))
// ---------------------------------------------------------------------------
__global__ void prep_pack(const float* __restrict__ xyz, float4* __restrict__ pack)
{
#pragma clang fp contract(off)
  int t = blockIdx.x * 256 + threadIdx.x;
  if (t < NB * NN) {
    float x = xyz[t * 3 + 0], y = xyz[t * 3 + 1], z = xyz[t * 3 + 2];
    float4 v; v.x = x; v.y = y; v.z = z; v.w = (x * x + y * y) + z * z;
    pack[t] = v;
  }
}

// ---------------------------------------------------------------------------
// Fold BN into weights, transpose to (c,o), remap layer0 channels so that
// c'=0..63 are features (orig 3..66) and c'=64..66 are rel-xyz (orig 0..2).
// ---------------------------------------------------------------------------
__global__ void prep_w(
    const float* __restrict__ w0, const float* __restrict__ b0,
    const float* __restrict__ g0, const float* __restrict__ be0,
    const float* __restrict__ m0, const float* __restrict__ v0,
    const float* __restrict__ w1, const float* __restrict__ b1,
    const float* __restrict__ g1, const float* __restrict__ be1,
    const float* __restrict__ m1, const float* __restrict__ v1,
    const float* __restrict__ w2, const float* __restrict__ b2,
    const float* __restrict__ g2, const float* __restrict__ be2,
    const float* __restrict__ m2, const float* __restrict__ v2,
    float* __restrict__ wT0, float* __restrict__ bb0,
    float* __restrict__ wT1, float* __restrict__ bb1,
    float* __restrict__ wT2, float* __restrict__ bb2)
{
  int t = blockIdx.x * 256 + threadIdx.x;
  if (t < 4288) {
    int c = t >> 6, o = t & 63;
    int oc = (c < 64) ? (c + 3) : (c - 64);
    float sc = g0[o] * rsqrtf(v0[o] + 1e-5f);
    wT0[t] = w0[o * 67 + oc] * sc;
  } else if (t < 4352) {
    int o = t - 4288;
    float sc = g0[o] * rsqrtf(v0[o] + 1e-5f);
    bb0[o] = (b0[o] - m0[o]) * sc + be0[o];
  } else if (t < 8448) {
    int u = t - 4352;
    int c = u >> 6, o = u & 63;
    float sc = g1[o] * rsqrtf(v1[o] + 1e-5f);
    wT1[u] = w1[o * 64 + c] * sc;
  } else if (t < 8512) {
    int o = t - 8448;
    float sc = g1[o] * rsqrtf(v1[o] + 1e-5f);
    bb1[o] = (b1[o] - m1[o]) * sc + be1[o];
  } else if (t < 16704) {
    int u = t - 8512;
    int c = u >> 7, o = u & 127;
    float sc = g2[o] * rsqrtf(v2[o] + 1e-5f);
    wT2[u] = w2[o * 64 + c] * sc;
  } else if (t < 16832) {
    int o = t - 16704;
    float sc = g2[o] * rsqrtf(v2[o] + 1e-5f);
    bb2[o] = (b2[o] - m2[o]) * sc + be2[o];
  }
}

// ---------------------------------------------------------------------------
// Ball query: one wave per query point. sqr = (sq_q + sq_x) - 2*dot with
// dot as Eigen-style fma chain over (x,y,z). Packed {x,y,z,sq} float4 loads
// (1 dwordx4/point). First 32 in-ball indices ascending; pad with first hit.
// ---------------------------------------------------------------------------
__global__ __launch_bounds__(256)
void ballq_kernel(const float4* __restrict__ pack,
                  const int* __restrict__ fps_idx, int* __restrict__ gidx)
{
#pragma clang fp contract(off)
  const int lane = threadIdx.x & 63;
  const int q = blockIdx.x * 4 + (threadIdx.x >> 6);
  const int b = q >> 11;
  const int s = q & 2047;
  const float4* __restrict__ PK = pack + (size_t)b * NN;
  const int cidx = fps_idx[b * NS + s];
  const float4 c4 = PK[cidx];
  const float cx = c4.x, cy = c4.y, cz = c4.z, csq = c4.w;
  int* __restrict__ g = gidx + (size_t)q * NK;
  int cnt = 0, firstn = 0;
  bool havefirst = false;
  for (int n0 = 0; n0 < NN; n0 += 64) {
    int n = n0 + lane;
    float4 p4 = PK[n];
    float dot = p4.x * cx;         // first gebp step: fma(a0,b0,0) == rn(a0*b0)
    dot = fmaf(p4.y, cy, dot);
    dot = fmaf(p4.z, cz, dot);
    float sqr = (csq + p4.w) - 2.0f * dot;
    bool in_ = (sqr <= R2);
    unsigned long long m = __ballot(in_);
    if (!havefirst && m) { firstn = n0 + __builtin_ctzll(m); havefirst = true; }
    int pos = cnt + __popcll(m & ((1ull << lane) - 1ull));
    if (in_ && pos < NK) g[pos] = n;
    cnt += __popcll(m);
    if (cnt >= NK) break;
  }
  if (cnt < NK && lane < NK - cnt) g[cnt + lane] = firstn;
}

// ---------------------------------------------------------------------------
// Grouped MLP + k-max: one block (256 thr) per query. Activations in LDS;
// weights staged per layer into one reused 32KB LDS buffer (R12 win).
// 2-row register blocking (R15 win): thread (k2,jj) computes rows k2 and
// k2+16, so every weight b128 read feeds TWO activation rows. Per-output
// accumulation order unchanged (c ascending) -> bit-identical. ReLU of
// layer 3 deferred past the max (relu(max) == max(relu)).
// ---------------------------------------------------------------------------
__global__ __launch_bounds__(256)
void mlp_kernel(const float* __restrict__ xyz, const float* __restrict__ feat,
                const int* __restrict__ gidx, const float* __restrict__ nxyz,
                const float* __restrict__ wT0, const float* __restrict__ bb0,
                const float* __restrict__ wT1, const float* __restrict__ bb1,
                const float* __restrict__ wT2, const float* __restrict__ bb2,
                float* __restrict__ out)
{
  const int q = blockIdx.x;
  const int b = q >> 11;
  const int tid = threadIdx.x;
  __shared__ int sg[32];
  __shared__ float A[32 * 76];    // stride 76 (=19*4): 16B-aligned rows
  __shared__ float Bf[32 * 76];
  __shared__ float Cf[32 * 132];
  __shared__ float Wb[8192];      // 32KB reused weight buffer (max 64*128)
  if (tid < 32) sg[tid] = gidx[(size_t)q * NK + tid];
  __syncthreads();
  {
    const int k = tid >> 3, j = tid & 7;
    const int p = sg[k];
    const float* fp = feat + ((size_t)b * NN + p) * NCF + j * 8;
    float4 f0 = *(const float4*)fp;
    float4 f1 = *(const float4*)(fp + 4);
    float* a = &A[k * 76 + j * 8];
    *(float4*)a = f0;
    *(float4*)(a + 4) = f1;
    if (j == 0) {
      float cx = nxyz[(size_t)q * 3 + 0];
      float cy = nxyz[(size_t)q * 3 + 1];
      float cz = nxyz[(size_t)q * 3 + 2];
      const float* pp = xyz + ((size_t)b * NN + p) * 3;
      A[k * 76 + 64] = pp[0] - cx;
      A[k * 76 + 65] = pp[1] - cy;
      A[k * 76 + 66] = pp[2] - cz;
    }
  }
  // ---- stage W0 (67*64 = 4288 floats = 1072 float4)
  {
    const float4* src = (const float4*)wT0;
    float4* dst = (float4*)Wb;
    for (int i = tid; i < 1072; i += 256) dst[i] = src[i];
  }
  __syncthreads();

  const int k2 = tid >> 4;       // row pair: k2 and k2+16
  const int jj = tid & 15;
#define FMA4x2(gA, gB, base)                                                \
  {                                                                         \
    float4 w = *(const float4*)(base);                                      \
    aA.x = fmaf(gA, w.x, aA.x); aA.y = fmaf(gA, w.y, aA.y);                 \
    aA.z = fmaf(gA, w.z, aA.z); aA.w = fmaf(gA, w.w, aA.w);                 \
    aB.x = fmaf(gB, w.x, aB.x); aB.y = fmaf(gB, w.y, aB.y);                 \
    aB.z = fmaf(gB, w.z, aB.z); aB.w = fmaf(gB, w.w, aB.w);                 \
  }
  // ---- layer 1: A[{k2,k2+16}][0..66] x Wb -> Bf (4 outs/thread/row)
  {
    const int o0 = jj * 4;
    float4 aA = *(const float4*)(bb0 + o0);
    float4 aB = aA;
    const float* AkA = &A[k2 * 76];
    const float* AkB = &A[(k2 + 16) * 76];
    for (int c = 0; c < 64; c += 4) {
      float4 gA = *(const float4*)(AkA + c);
      float4 gB = *(const float4*)(AkB + c);
      FMA4x2(gA.x, gB.x, Wb + (c + 0) * 64 + o0);
      FMA4x2(gA.y, gB.y, Wb + (c + 1) * 64 + o0);
      FMA4x2(gA.z, gB.z, Wb + (c + 2) * 64 + o0);
      FMA4x2(gA.w, gB.w, Wb + (c + 3) * 64 + o0);
    }
    float4 gA = *(const float4*)(AkA + 64);   // elems 64..66 (+pad 67 unused)
    float4 gB = *(const float4*)(AkB + 64);
    FMA4x2(gA.x, gB.x, Wb + 64 * 64 + o0);
    FMA4x2(gA.y, gB.y, Wb + 65 * 64 + o0);
    FMA4x2(gA.z, gB.z, Wb + 66 * 64 + o0);
    float4 rA; rA.x = fmaxf(aA.x, 0.f); rA.y = fmaxf(aA.y, 0.f);
    rA.z = fmaxf(aA.z, 0.f); rA.w = fmaxf(aA.w, 0.f);
    float4 rB; rB.x = fmaxf(aB.x, 0.f); rB.y = fmaxf(aB.y, 0.f);
    rB.z = fmaxf(aB.z, 0.f); rB.w = fmaxf(aB.w, 0.f);
    *(float4*)&Bf[k2 * 76 + o0] = rA;
    *(float4*)&Bf[(k2 + 16) * 76 + o0] = rB;
  }
  __syncthreads();
  // ---- stage W1 (64*64 = 4096 floats = 1024 float4)
  {
    const float4* src = (const float4*)wT1;
    float4* dst = (float4*)Wb;
    for (int i = tid; i < 1024; i += 256) dst[i] = src[i];
  }
  __syncthreads();
  // ---- layer 2: Bf[{k2,k2+16}][0..63] x Wb -> A
  {
    const int o0 = jj * 4;
    float4 aA = *(const float4*)(bb1 + o0);
    float4 aB = aA;
    const float* BkA = &Bf[k2 * 76];
    const float* BkB = &Bf[(k2 + 16) * 76];
    for (int c = 0; c < 64; c += 4) {
      float4 gA = *(const float4*)(BkA + c);
      float4 gB = *(const float4*)(BkB + c);
      FMA4x2(gA.x, gB.x, Wb + (c + 0) * 64 + o0);
      FMA4x2(gA.y, gB.y, Wb + (c + 1) * 64 + o0);
      FMA4x2(gA.z, gB.z, Wb + (c + 2) * 64 + o0);
      FMA4x2(gA.w, gB.w, Wb + (c + 3) * 64 + o0);
    }
    float4 rA; rA.x = fmaxf(aA.x, 0.f); rA.y = fmaxf(aA.y, 0.f);
    rA.z = fmaxf(aA.z, 0.f); rA.w = fmaxf(aA.w, 0.f);
    float4 rB; rB.x = fmaxf(aB.x, 0.f); rB.y = fmaxf(aB.y, 0.f);
    rB.z = fmaxf(aB.z, 0.f); rB.w = fmaxf(aB.w, 0.f);
    *(float4*)&A[k2 * 76 + o0] = rA;
    *(float4*)&A[(k2 + 16) * 76 + o0] = rB;
  }
  __syncthreads();
  // ---- stage W2 (64*128 = 8192 floats = 2048 float4)
  {
    const float4* src = (const float4*)wT2;
    float4* dst = (float4*)Wb;
    for (int i = tid; i < 2048; i += 256) dst[i] = src[i];
  }
  __syncthreads();
  // ---- layer 3: A[{k2,k2+16}][0..63] x Wb -> Cf (8 outs/thread/row; no relu)
  {
    const int t0 = jj * 8;
    float4 aA0 = *(const float4*)(bb2 + t0);
    float4 aA1 = *(const float4*)(bb2 + t0 + 4);
    float4 aB0 = aA0, aB1 = aA1;
    const float* AkA = &A[k2 * 76];
    const float* AkB = &A[(k2 + 16) * 76];
#define FMA8x2(gA, gB, base)                                                \
    {                                                                       \
      float4 w0v = *(const float4*)(base);                                  \
      float4 w1v = *(const float4*)((base) + 4);                            \
      aA0.x = fmaf(gA, w0v.x, aA0.x); aA0.y = fmaf(gA, w0v.y, aA0.y);       \
      aA0.z = fmaf(gA, w0v.z, aA0.z); aA0.w = fmaf(gA, w0v.w, aA0.w);       \
      aA1.x = fmaf(gA, w1v.x, aA1.x); aA1.y = fmaf(gA, w1v.y, aA1.y);       \
      aA1.z = fmaf(gA, w1v.z, aA1.z); aA1.w = fmaf(gA, w1v.w, aA1.w);       \
      aB0.x = fmaf(gB, w0v.x, aB0.x); aB0.y = fmaf(gB, w0v.y, aB0.y);       \
      aB0.z = fmaf(gB, w0v.z, aB0.z); aB0.w = fmaf(gB, w0v.w, aB0.w);       \
      aB1.x = fmaf(gB, w1v.x, aB1.x); aB1.y = fmaf(gB, w1v.y, aB1.y);       \
      aB1.z = fmaf(gB, w1v.z, aB1.z); aB1.w = fmaf(gB, w1v.w, aB1.w);       \
    }
    for (int c = 0; c < 64; c += 4) {
      float4 gA = *(const float4*)(AkA + c);
      float4 gB = *(const float4*)(AkB + c);
      FMA8x2(gA.x, gB.x, Wb + (c + 0) * 128 + t0);
      FMA8x2(gA.y, gB.y, Wb + (c + 1) * 128 + t0);
      FMA8x2(gA.z, gB.z, Wb + (c + 2) * 128 + t0);
      FMA8x2(gA.w, gB.w, Wb + (c + 3) * 128 + t0);
    }
    float* oA = &Cf[k2 * 132 + t0];
    *(float4*)(oA + 0) = aA0;
    *(float4*)(oA + 4) = aA1;
    float* oB = &Cf[(k2 + 16) * 132 + t0];
    *(float4*)(oB + 0) = aB0;
    *(float4*)(oB + 4) = aB1;
  }
  __syncthreads();
  // ---- max over k, relu, store
  if (tid < 128) {
    float m = Cf[tid];
    for (int kk = 1; kk < 32; ++kk) m = fmaxf(m, Cf[kk * 132 + tid]);
    out[(size_t)(NB * NS * 3) + (size_t)q * 128 + tid] = fmaxf(m, 0.0f);
  }
}

extern "C" void kernel_launch(void* const* d_in, const int* in_sizes, int n_in,
                              void* d_out, int out_size, void* d_ws, size_t ws_size,
                              hipStream_t stream)
{
  (void)in_sizes; (void)n_in; (void)out_size; (void)ws_size;
  const float* xyz  = (const float*)d_in[0];
  const float* feat = (const float*)d_in[1];
  const float* w0 = (const float*)d_in[2];
  const float* b0 = (const float*)d_in[3];
  const float* g0 = (const float*)d_in[4];
  const float* be0 = (const float*)d_in[5];
  const float* m0 = (const float*)d_in[6];
  const float* v0 = (const float*)d_in[7];
  const float* w1 = (const float*)d_in[8];
  const float* b1 = (const float*)d_in[9];
  const float* g1 = (const float*)d_in[10];
  const float* be1 = (const float*)d_in[11];
  const float* m1 = (const float*)d_in[12];
  const float* v1 = (const float*)d_in[13];
  const float* w2 = (const float*)d_in[14];
  const float* b2 = (const float*)d_in[15];
  const float* g2 = (const float*)d_in[16];
  const float* be2 = (const float*)d_in[17];
  const float* m2 = (const float*)d_in[18];
  const float* v2 = (const float*)d_in[19];

  float* ws = (float*)d_ws;
  int* fpsi = (int*)(ws + WS_FPSIDX);
  float4* pack = (float4*)(ws + WS_PACK);
  int* gidx = (int*)(ws + WS_GIDX);
  float* wT0 = ws + WS_WT0; float* bb0 = ws + WS_BB0;
  float* wT1 = ws + WS_WT1; float* bb1 = ws + WS_BB1;
  float* wT2 = ws + WS_WT2; float* bb2 = ws + WS_BB2;
  float* nxyz = (float*)d_out;

  hipLaunchKernelGGL(prep_pack, dim3((NB * NN + 255) / 256), dim3(256), 0, stream,
                     xyz, pack);
  hipLaunchKernelGGL(prep_w, dim3(66), dim3(256), 0, stream,
                     w0, b0, g0, be0, m0, v0,
                     w1, b1, g1, be1, m1, v1,
                     w2, b2, g2, be2, m2, v2,
                     wT0, bb0, wT1, bb1, wT2, bb2);
  hipLaunchKernelGGL(fps_kernel, dim3(NB), dim3(1024), 0, stream,
                     xyz, fpsi, nxyz);
  hipLaunchKernelGGL(ballq_kernel, dim3(NB * NS / 4), dim3(256), 0, stream,
                     pack, fpsi, gidx);
  hipLaunchKernelGGL(mlp_kernel, dim3(NB * NS), dim3(256), 0, stream,
                     xyz, feat, gidx, nxyz,
                     wT0, bb0, wT1, bb1, wT2, bb2, (float*)d_out);
}